// Round 2
// baseline (512.061 us; speedup 1.0000x reference)
//
#include <hip/hip_runtime.h>
#include <hip/hip_bf16.h>

typedef unsigned short u16;
typedef __attribute__((ext_vector_type(8))) short short8;
typedef __attribute__((ext_vector_type(4))) float f32x4;

#define NE 131072

// ws layout in u16 elements (bf16 transposed weights, [n][k] row-major)
#define OFF_WA 0        // 4 x [256][256]
#define OFF_WB 262144   // 4 x [128][256]
#define OFF_WF 393216   // 4 x [128][128]
#define OFF_WE 458752   // [128][32]
#define OFF_WS 462848   // [128]

// async global->LDS, 16B per lane, lane i lands at lds_base + 16*i
#define ASYNC16(gp, lp) __builtin_amdgcn_global_load_lds( \
    (const __attribute__((address_space(1))) unsigned int*)(gp), \
    (__attribute__((address_space(3))) unsigned int*)(lp), 16, 0, 0)
// wait lgkmcnt(0) only (vmcnt=63 no-wait, expcnt=7 no-wait): ensures ds_read data
// is in VGPRs before we overwrite the LDS region with the next DMA chunk.
#define LGKM0() __builtin_amdgcn_s_waitcnt(0xC07F)
// per-wave wait: all of this wave's outstanding global_load_lds have landed in
// LDS (vmcnt counts them; retire = LDS written). asm with "memory" clobber so
// the compiler cannot hoist the dependent ds_reads above it.
#define VM0() asm volatile("s_waitcnt vmcnt(0)" ::: "memory")

__device__ __forceinline__ float b2f(u16 v) {
    unsigned int u = ((unsigned int)v) << 16;
    float f;
    __builtin_memcpy(&f, &u, 4);
    return f;
}
__device__ __forceinline__ u16 f2b(float f) {
    __hip_bfloat16 h = __float2bfloat16(f);
    u16 u;
    __builtin_memcpy(&u, &h, 2);
    return u;
}
__device__ __forceinline__ short8 pack8(f32x4 a, f32x4 b) {
    short8 p;
    p[0] = (short)f2b(a.x); p[1] = (short)f2b(a.y);
    p[2] = (short)f2b(a.z); p[3] = (short)f2b(a.w);
    p[4] = (short)f2b(b.x); p[5] = (short)f2b(b.y);
    p[6] = (short)f2b(b.z); p[7] = (short)f2b(b.w);
    return p;
}

#define MFMA16(a, b, c) __builtin_amdgcn_mfma_f32_16x16x32_bf16(a, b, c, 0, 0, 0)

struct BiasP {
    const float* ba[4];
    const float* bb[4];
};

// ---- per-wave async weight staging (each wave stages its own 4-KB quarter) ----
// Wb quarter layout, stage A (chunk = 32 k): [n_local(64)][32k] u16
__device__ __forceinline__ void issueA(const u16* ws, u16* Wb, int wave, int lane, int m, int kk) {
    const u16* gp = ws + OFF_WA + m * 65536
                  + (size_t)(wave * 64 + (lane >> 2)) * 256 + kk * 32 + (lane & 3) * 8;
    u16* lp = Wb + wave * 2048;
    #pragma unroll
    for (int j = 0; j < 4; j++) ASYNC16(gp + j * 4096, lp + j * 512);
}
// stage B (chunk = 64 k): [n_local(32)][8 slots of 8k, slot XOR-swizzled by n&7]
__device__ __forceinline__ void issueB(const u16* ws, u16* Wb, int wave, int lane, int m, int kc) {
    int nl = lane >> 3, sg = (lane & 7) ^ (nl & 7);
    const u16* gp = ws + OFF_WB + m * 32768
                  + (size_t)(wave * 32 + nl) * 256 + kc * 64 + sg * 8;
    u16* lp = Wb + wave * 2048;
    #pragma unroll
    for (int j = 0; j < 4; j++) ASYNC16(gp + j * 2048, lp + j * 512);
}
__device__ __forceinline__ void issueC(const u16* ws, u16* Wb, int wave, int lane, int m, int kc) {
    int nl = lane >> 3, sg = (lane & 7) ^ (nl & 7);
    const u16* gp = ws + OFF_WF + m * 16384
                  + (size_t)(wave * 32 + nl) * 128 + kc * 64 + sg * 8;
    u16* lp = Wb + wave * 2048;
    #pragma unroll
    for (int j = 0; j < 4; j++) ASYNC16(gp + j * 1024, lp + j * 512);
}

// LDS-tiled transpose prep: coalesced reads AND writes.
__global__ __launch_bounds__(256)
void prep_kernel(const float* __restrict__ W1a, const float* __restrict__ W2a,
                 const float* __restrict__ W3a, const float* __restrict__ W4a,
                 const float* __restrict__ W1b, const float* __restrict__ W2b,
                 const float* __restrict__ W3b, const float* __restrict__ W4b,
                 const float* __restrict__ Wf,  u16* __restrict__ ws) {
    __shared__ __align__(16) u16 T[64 * 80];

    const int y = blockIdx.y;
    const int t = threadIdx.x;
    const float* in;
    int K, N;
    if (y < 4)      { in = (y == 0) ? W1a : (y == 1) ? W2a : (y == 2) ? W3a : W4a; K = 256; N = 256; }
    else if (y < 8) { in = (y == 4) ? W1b : (y == 5) ? W2b : (y == 6) ? W3b : W4b; K = 256; N = 128; }
    else            { in = Wf; K = 545; N = 128; }

    const int ntilesN = N / 64;
    const int ktiles = (K + 63) / 64;
    const int kt = blockIdx.x / ntilesN;
    const int nt = blockIdx.x - kt * ntilesN;
    if (kt >= ktiles) return;
    const int kbase = kt * 64, nbase = nt * 64;

    {
        int tn = (t & 15) * 4;
        int tk = t >> 4;
        #pragma unroll
        for (int r = 0; r < 4; r++) {
            int k = kbase + tk + 16 * r;
            if (k < K) {
                float4 v = *(const float4*)(in + (size_t)k * N + nbase + tn);
                T[(tn + 0) * 80 + tk + 16 * r] = f2b(v.x);
                T[(tn + 1) * 80 + tk + 16 * r] = f2b(v.y);
                T[(tn + 2) * 80 + tk + 16 * r] = f2b(v.z);
                T[(tn + 3) * 80 + tk + 16 * r] = f2b(v.w);
            }
        }
    }
    __syncthreads();
    {
        int n = t >> 2;
        int kc = (t & 3) * 16;
        int n_out = nbase + n;
        const u16* src = &T[n * 80 + kc];
        if (y < 4) {
            u16* dst = ws + OFF_WA + y * 65536 + (size_t)n_out * 256 + kbase + kc;
            *(short8*)dst = *(const short8*)src;
            *(short8*)(dst + 8) = *(const short8*)(src + 8);
        } else if (y < 8) {
            u16* dst = ws + OFF_WB + (y - 4) * 32768 + (size_t)n_out * 256 + kbase + kc;
            *(short8*)dst = *(const short8*)src;
            *(short8*)(dst + 8) = *(const short8*)(src + 8);
        } else if (kbase < 512) {
            u16* dst = ws + OFF_WF + (kbase >> 7) * 16384 + (size_t)n_out * 128 + (kbase & 127) + kc;
            *(short8*)dst = *(const short8*)src;
            *(short8*)(dst + 8) = *(const short8*)(src + 8);
        } else {
            #pragma unroll
            for (int j = 0; j < 16; j++) {
                int k = kbase + kc + j;
                if (k < 545) {
                    u16 v = src[j];
                    if (k == 512)      ws[OFF_WS + n_out] = v;
                    else               ws[OFF_WE + n_out * 32 + (k - 513)] = v;
                }
            }
        }
    }
}

// 32 edges/block, 4 waves, ~74 KB LDS -> 2 blocks/CU.
// Sync scheme: per-chunk __syncthreads are GONE. Each wave stages and reads
// only its own private Wb quarter, so chunk arrival is a per-wave
// s_waitcnt vmcnt(0) (VM0), not a block barrier. Block barriers remain only
// at true cross-wave handoffs:
//   gather->Xs/Xd (1), Hs ready (per m), Gs ready (per m), epilogue staging.
// Hazard audit under wave drift:
//   - Hs overwrite at end of A(m+1) vs B(m) reads: fenced by BARRIER_B(m).
//   - Gs overwrite at end of B(m+1) vs C(m) reads: fenced by BARRIER_A(m+1).
//   - os (aliases Xs) writes vs A(3) Xs reads: fenced by BARRIER_B(3).
//   - Wb read-before-DMA-overwrite: per-wave LGKM0 before each issue.
// Streaming traffic (x gather, edge_attr, out) is non-temporal so the
// weights stay L2-resident for the global_load_lds path.
__global__ __launch_bounds__(256, 2)
void fused_kernel(const float* __restrict__ x, const int* __restrict__ ei,
                  const float* __restrict__ ea, const u16* __restrict__ ws,
                  BiasP bp, const float* __restrict__ bfp, float* __restrict__ out) {
    __shared__ __align__(16) u16 Xs[32][264];
    __shared__ __align__(16) u16 Xd[32][264];
    __shared__ __align__(16) u16 Hs[32][264];
    __shared__ __align__(16) u16 Gs[32][136];
    __shared__ __align__(16) u16 Wb[8192];   // 16 KB, 4-KB quarter per wave
    __shared__ float scos[32];

    const int t = threadIdx.x;
    const int wave = t >> 6;
    const int lane = t & 63;
    const int l15 = lane & 15;
    const int g = lane >> 4;
    const int e0 = blockIdx.x * 32;
    const f32x4 zero4 = {0.f, 0.f, 0.f, 0.f};

    // Hedge: detect int64 edge_index (sampled high words all zero) vs int32.
    bool idx64 = true;
    #pragma unroll
    for (int i = 1; i < 16; i += 2) { idx64 = idx64 && (ei[i] == 0); }

    // fire the first weight chunk now; it lands during the gather
    issueA(ws, Wb, wave, lane, 0, 0);

    // ---- gather (f32 -> bf16 tiles) + cosine similarity in one pass ----
    {
        int edge = t >> 3;
        int c = t & 7;
        int pos = e0 + edge;
        int is = idx64 ? ei[2 * pos] : ei[pos];
        int id = idx64 ? ei[2 * (NE + pos)] : ei[NE + pos];
        const float* rs = x + (size_t)is * 256 + c * 32;
        const float* rd = x + (size_t)id * 256 + c * 32;
        float dot = 0.f, ss = 0.f, dd = 0.f;
        #pragma unroll
        for (int i = 0; i < 4; i++) {
            f32x4 s0 = __builtin_nontemporal_load((const f32x4*)(rs + i * 8));
            f32x4 s1 = __builtin_nontemporal_load((const f32x4*)(rs + i * 8 + 4));
            f32x4 d0 = __builtin_nontemporal_load((const f32x4*)(rd + i * 8));
            f32x4 d1 = __builtin_nontemporal_load((const f32x4*)(rd + i * 8 + 4));
            dot += s0.x * d0.x + s0.y * d0.y + s0.z * d0.z + s0.w * d0.w
                 + s1.x * d1.x + s1.y * d1.y + s1.z * d1.z + s1.w * d1.w;
            ss  += s0.x * s0.x + s0.y * s0.y + s0.z * s0.z + s0.w * s0.w
                 + s1.x * s1.x + s1.y * s1.y + s1.z * s1.z + s1.w * s1.w;
            dd  += d0.x * d0.x + d0.y * d0.y + d0.z * d0.z + d0.w * d0.w
                 + d1.x * d1.x + d1.y * d1.y + d1.z * d1.z + d1.w * d1.w;
            *(short8*)(&Xs[edge][c * 32 + i * 8]) = pack8(s0, s1);
            *(short8*)(&Xd[edge][c * 32 + i * 8]) = pack8(d0, d1);
        }
        dot += __shfl_xor(dot, 1); ss += __shfl_xor(ss, 1); dd += __shfl_xor(dd, 1);
        dot += __shfl_xor(dot, 2); ss += __shfl_xor(ss, 2); dd += __shfl_xor(dd, 2);
        dot += __shfl_xor(dot, 4); ss += __shfl_xor(ss, 4); dd += __shfl_xor(dd, 4);
        if (c == 0) {
            float ns = fmaxf(sqrtf(ss), 1e-8f);
            float nd = fmaxf(sqrtf(dd), 1e-8f);
            scos[edge] = dot / (ns * nd);
        }
    }
    __syncthreads();   // Xs/Xd/scos visible to all waves (the ONE gather barrier)

    const int colA = wave * 64;
    const int colC = wave * 32;

    // ---- hoisted constants (all global loads live before the m-loop) ----
    short8 eaA[2];
    #pragma unroll
    for (int mt = 0; mt < 2; mt++) {
        const float* er = ea + (size_t)(e0 + mt * 16 + l15) * 32 + g * 8;
        f32x4 a = __builtin_nontemporal_load((const f32x4*)(er));
        f32x4 b = __builtin_nontemporal_load((const f32x4*)(er + 4));
        eaA[mt] = pack8(a, b);
    }
    short8 eaB[2];
    float epi_b[2], epi_w[2];
    #pragma unroll
    for (int nt = 0; nt < 2; nt++) {
        int col = colC + nt * 16 + l15;
        eaB[nt] = *(const short8*)(ws + OFF_WE + col * 32 + g * 8);
        epi_b[nt] = bfp[col];
        epi_w[nt] = b2f(ws[OFF_WS + col]);
    }
    float biasA[4][4], biasB[4][2];
    #pragma unroll
    for (int m = 0; m < 4; m++) {
        #pragma unroll
        for (int nt = 0; nt < 4; nt++) biasA[m][nt] = bp.ba[m][colA + nt * 16 + l15];
        #pragma unroll
        for (int nt = 0; nt < 2; nt++) biasB[m][nt] = bp.bb[m][colC + nt * 16 + l15];
    }

    // ---- LDS read base pointers ----
    const u16* xsb0 = &Xs[l15][g * 8];      const u16* xsb1 = &Xs[16 + l15][g * 8];
    const u16* xdb0 = &Xd[l15][g * 8];      const u16* xdb1 = &Xd[16 + l15][g * 8];
    const u16* hrb0 = &Hs[l15][g * 8];      const u16* hrb1 = &Hs[16 + l15][g * 8];
    const u16* grb0 = &Gs[l15][g * 8];      const u16* grb1 = &Gs[16 + l15][g * 8];
    const u16* wba  = Wb + wave * 2048 + l15 * 32 + g * 8;    // stage A frags
    const u16* wbb  = Wb + wave * 2048 + l15 * 64;            // stage B/C frags

    f32x4 Facc[2][2];
    #pragma unroll
    for (int a = 0; a < 2; a++) {
        #pragma unroll
        for (int b = 0; b < 2; b++) Facc[a][b] = zero4;
    }

    #pragma unroll
    for (int m = 0; m < 4; m++) {
        // ===== stage A: H = relu(A @ Wa + ba) ===== (8 chunks of 32-k)
        f32x4 accA[2][4];
        #pragma unroll
        for (int a = 0; a < 2; a++) {
            #pragma unroll
            for (int b = 0; b < 4; b++) accA[a][b] = zero4;
        }
        #pragma unroll
        for (int kk = 0; kk < 8; kk++) {
            VM0();                               // this wave's chunk kk landed
            short8 wf[4];
            #pragma unroll
            for (int nt = 0; nt < 4; nt++) wf[nt] = *(const short8*)(wba + nt * 512);
            short8 s0, s1, d0, d1;
            if (m != 1) { s0 = *(const short8*)(xsb0 + kk * 32); s1 = *(const short8*)(xsb1 + kk * 32); }
            if (m != 0) { d0 = *(const short8*)(xdb0 + kk * 32); d1 = *(const short8*)(xdb1 + kk * 32); }
            LGKM0();                             // frag data in regs before overwrite
            if (kk < 7) issueA(ws, Wb, wave, lane, m, kk + 1);
            else        issueB(ws, Wb, wave, lane, m, 0);
            short8 af[2];
            if (m == 0)      { af[0] = s0; af[1] = s1; }
            else if (m == 1) { af[0] = d0; af[1] = d1; }
            else {
                #pragma unroll
                for (int mt = 0; mt < 2; mt++) {
                    short8 s = mt ? s1 : s0, d = mt ? d1 : d0, rr;
                    #pragma unroll
                    for (int j = 0; j < 8; j++) {
                        float fs = b2f((u16)s[j]);
                        float fd = b2f((u16)d[j]);
                        rr[j] = (short)f2b((m == 2) ? (fs - fd) : (fs * fd));
                    }
                    af[mt] = rr;
                }
            }
            #pragma unroll
            for (int mt = 0; mt < 2; mt++) {
                #pragma unroll
                for (int nt = 0; nt < 4; nt++) {
                    accA[mt][nt] = MFMA16(af[mt], wf[nt], accA[mt][nt]);
                }
            }
        }
        #pragma unroll
        for (int nt = 0; nt < 4; nt++) {
            int col = colA + nt * 16 + l15;
            #pragma unroll
            for (int mt = 0; mt < 2; mt++) {
                #pragma unroll
                for (int rg = 0; rg < 4; rg++) {
                    int row = mt * 16 + g * 4 + rg;
                    Hs[row][col] = f2b(fmaxf(accA[mt][nt][rg] + biasA[m][nt], 0.f));
                }
            }
        }
        __syncthreads();                         // BARRIER_A: Hs ready

        // ===== stage B: G = relu(H @ Wb + bb) ===== (4 chunks of 64-k)
        f32x4 accB[2][2];
        #pragma unroll
        for (int a = 0; a < 2; a++) {
            #pragma unroll
            for (int b = 0; b < 2; b++) accB[a][b] = zero4;
        }
        #pragma unroll
        for (int kc = 0; kc < 4; kc++) {
            VM0();                               // this wave's chunk landed
            short8 wf[2][2], hf[2][2];
            #pragma unroll
            for (int kk2 = 0; kk2 < 2; kk2++) {
                const int slot = ((kk2 * 4 + g) ^ (l15 & 7)) * 8;
                wf[kk2][0] = *(const short8*)(wbb + slot);
                wf[kk2][1] = *(const short8*)(wbb + 1024 + slot);
                hf[kk2][0] = *(const short8*)(hrb0 + kc * 64 + kk2 * 32);
                hf[kk2][1] = *(const short8*)(hrb1 + kc * 64 + kk2 * 32);
            }
            LGKM0();
            if (kc < 3) issueB(ws, Wb, wave, lane, m, kc + 1);
            else        issueC(ws, Wb, wave, lane, m, 0);
            #pragma unroll
            for (int kk2 = 0; kk2 < 2; kk2++) {
                #pragma unroll
                for (int mt = 0; mt < 2; mt++) {
                    #pragma unroll
                    for (int nt = 0; nt < 2; nt++) {
                        accB[mt][nt] = MFMA16(hf[kk2][mt], wf[kk2][nt], accB[mt][nt]);
                    }
                }
            }
        }
        #pragma unroll
        for (int nt = 0; nt < 2; nt++) {
            int col = colC + nt * 16 + l15;
            #pragma unroll
            for (int mt = 0; mt < 2; mt++) {
                #pragma unroll
                for (int rg = 0; rg < 4; rg++) {
                    int row = mt * 16 + g * 4 + rg;
                    Gs[row][col] = f2b(fmaxf(accB[mt][nt][rg] + biasB[m][nt], 0.f));
                }
            }
        }
        __syncthreads();                         // BARRIER_B: Gs ready

        // ===== stage C: Facc += G @ WfT_m ===== (2 chunks of 64-k)
        #pragma unroll
        for (int kc = 0; kc < 2; kc++) {
            VM0();                               // this wave's chunk landed
            short8 wf[2][2], gf[2][2];
            #pragma unroll
            for (int kk2 = 0; kk2 < 2; kk2++) {
                const int slot = ((kk2 * 4 + g) ^ (l15 & 7)) * 8;
                wf[kk2][0] = *(const short8*)(wbb + slot);
                wf[kk2][1] = *(const short8*)(wbb + 1024 + slot);
                gf[kk2][0] = *(const short8*)(grb0 + kc * 64 + kk2 * 32);
                gf[kk2][1] = *(const short8*)(grb1 + kc * 64 + kk2 * 32);
            }
            LGKM0();
            if (kc == 0)     issueC(ws, Wb, wave, lane, m, 1);
            else if (m < 3)  issueA(ws, Wb, wave, lane, m + 1, 0);
            #pragma unroll
            for (int kk2 = 0; kk2 < 2; kk2++) {
                #pragma unroll
                for (int mt = 0; mt < 2; mt++) {
                    #pragma unroll
                    for (int nt = 0; nt < 2; nt++) {
                        Facc[mt][nt] = MFMA16(gf[kk2][mt], wf[kk2][nt], Facc[mt][nt]);
                    }
                }
            }
        }
        // no barrier here: next A reads only Xs/Xd (stable) + private Wb;
        // Gs overwrite in B(m+1) is fenced by BARRIER_A(m+1).
    }

    // ===== edge_attr contribution (fragments pre-loaded) =====
    #pragma unroll
    for (int mt = 0; mt < 2; mt++) {
        #pragma unroll
        for (int nt = 0; nt < 2; nt++) {
            Facc[mt][nt] = MFMA16(eaA[mt], eaB[nt], Facc[mt][nt]);
        }
    }

    // ===== epilogue: + s*Wf[512] + bf, tanh, stage f32 in LDS, coalesced store =====
    float* os = (float*)&Xs[0][0];   // reuse Xs: 32 x 132 f32 = 16896 B (exact fit)
    #pragma unroll
    for (int nt = 0; nt < 2; nt++) {
        int col = colC + nt * 16 + l15;
        #pragma unroll
        for (int mt = 0; mt < 2; mt++) {
            #pragma unroll
            for (int rg = 0; rg < 4; rg++) {
                int row = mt * 16 + g * 4 + rg;
                float v = Facc[mt][nt][rg] + scos[row] * epi_w[nt] + epi_b[nt];
                v = fminf(fmaxf(v, -15.f), 15.f);
                float e2 = __expf(2.f * v);
                os[row * 132 + col] = (e2 - 1.f) / (e2 + 1.f);
            }
        }
    }
    __syncthreads();
    {
        int row = t >> 3, c = t & 7;
        float* op = out + (size_t)(e0 + row) * 128 + c * 16;
        const float* sp = os + row * 132 + c * 16;
        #pragma unroll
        for (int i = 0; i < 4; i++) {
            f32x4 v = *(const f32x4*)(sp + i * 4);
            __builtin_nontemporal_store(v, (f32x4*)(op + i * 4));
        }
    }
}

extern "C" void kernel_launch(void* const* d_in, const int* in_sizes, int n_in,
                              void* d_out, int out_size, void* d_ws, size_t ws_size,
                              hipStream_t stream) {
    u16* ws = (u16*)d_ws;
    prep_kernel<<<dim3(18, 9), 256, 0, stream>>>(
        (const float*)d_in[3],  (const float*)d_in[7],  (const float*)d_in[11], (const float*)d_in[15],
        (const float*)d_in[5],  (const float*)d_in[9],  (const float*)d_in[13], (const float*)d_in[17],
        (const float*)d_in[19], ws);

    BiasP bp;
    bp.ba[0] = (const float*)d_in[4];  bp.ba[1] = (const float*)d_in[8];
    bp.ba[2] = (const float*)d_in[12]; bp.ba[3] = (const float*)d_in[16];
    bp.bb[0] = (const float*)d_in[6];  bp.bb[1] = (const float*)d_in[10];
    bp.bb[2] = (const float*)d_in[14]; bp.bb[3] = (const float*)d_in[18];

    fused_kernel<<<NE / 32, 256, 0, stream>>>(
        (const float*)d_in[0], (const int*)d_in[1], (const float*)d_in[2], ws,
        bp, (const float*)d_in[20], (float*)d_out);
}

// Round 3
// 428.293 us; speedup vs baseline: 1.1956x; 1.1956x over previous
//
#include <hip/hip_runtime.h>
#include <hip/hip_bf16.h>

typedef unsigned short u16;
typedef __attribute__((ext_vector_type(8))) short short8;
typedef __attribute__((ext_vector_type(4))) float f32x4;

#define NE 131072

// ws layout in u16 elements (bf16 transposed weights, [n][k] row-major)
#define OFF_WA 0        // 4 x [256][256]
#define OFF_WB 262144   // 4 x [128][256]
#define OFF_WF 393216   // 4 x [128][128]
#define OFF_WE 458752   // [128][32]
#define OFF_WS 462848   // [128]

// async global->LDS, 16B per lane, lane i lands at lds_base + 16*i
#define ASYNC16(gp, lp) __builtin_amdgcn_global_load_lds( \
    (const __attribute__((address_space(1))) unsigned int*)(gp), \
    (__attribute__((address_space(3))) unsigned int*)(lp), 16, 0, 0)
// wait lgkmcnt(0) only: ds_read data in VGPRs before we re-DMA that LDS half.
#define LGKM0() __builtin_amdgcn_s_waitcnt(0xC07F)
// counted per-wave wait: the oldest chunk (2 loads) has landed, the next
// chunk's 2 loads stay in flight. memory clobber: no ds_read hoisting.
#define WAIT2() asm volatile("s_waitcnt vmcnt(2)" ::: "memory")
#define VM0()   asm volatile("s_waitcnt vmcnt(0)" ::: "memory")

__device__ __forceinline__ float b2f(u16 v) {
    unsigned int u = ((unsigned int)v) << 16;
    float f;
    __builtin_memcpy(&f, &u, 4);
    return f;
}
__device__ __forceinline__ u16 f2b(float f) {
    __hip_bfloat16 h = __float2bfloat16(f);
    u16 u;
    __builtin_memcpy(&u, &h, 2);
    return u;
}
__device__ __forceinline__ short8 pack8(f32x4 a, f32x4 b) {
    short8 p;
    p[0] = (short)f2b(a.x); p[1] = (short)f2b(a.y);
    p[2] = (short)f2b(a.z); p[3] = (short)f2b(a.w);
    p[4] = (short)f2b(b.x); p[5] = (short)f2b(b.y);
    p[6] = (short)f2b(b.z); p[7] = (short)f2b(b.w);
    return p;
}

#define MFMA16(a, b, c) __builtin_amdgcn_mfma_f32_16x16x32_bf16(a, b, c, 0, 0, 0)

struct BiasP {
    const float* ba[4];
    const float* bb[4];
};

// ---- uniform 2-KB weight chunks, wave-private double buffer ----
// Chunk = [32 weight rows][32 k] bf16 = 2 KB. Per block: per m-group 28 chunks
// (A: 16 = 8 kk x 2 col-halves, B: 8, C: 4) -> 112 total. Chunk gc lives in
// half (gc&1) of the wave's 4-KB quarter. k-slot is XOR-swizzled by
// ((row>>1)&3) on BOTH the DMA source and the LDS read (bank-conflict fix).
__device__ __forceinline__ void issue_chunk(const u16* __restrict__ ws, u16* Wb,
                                            int wave, int lane, int gc) {
    if (gc >= 112) return;
    const int m = gc / 28;
    const int c = gc - m * 28;
    const int r = lane >> 2;                        // row 0..15 within 16-row group
    const int slot = (lane & 3) ^ ((lane >> 3) & 3); // pre-swizzled k-slot
    u16* lp = Wb + wave * 2048 + (gc & 1) * 1024;
    const u16* gp;
    int rstride;
    if (c < 16) {            // stage A: Wa_m [256][256], wave cols = wave*64 + (c&1)*32
        int kk = c >> 1, nh = c & 1;
        gp = ws + OFF_WA + m * 65536
           + (size_t)(wave * 64 + nh * 32 + r) * 256 + kk * 32 + slot * 8;
        rstride = 16 * 256;
    } else if (c < 24) {     // stage B: Wb_m [128][256], wave cols = wave*32
        int kc = c - 16;
        gp = ws + OFF_WB + m * 32768
           + (size_t)(wave * 32 + r) * 256 + kc * 32 + slot * 8;
        rstride = 16 * 256;
    } else {                 // stage C: Wf_m [128][128]
        int cc = c - 24;
        gp = ws + OFF_WF + m * 16384
           + (size_t)(wave * 32 + r) * 128 + cc * 32 + slot * 8;
        rstride = 16 * 128;
    }
    ASYNC16(gp, lp);
    ASYNC16(gp + rstride, lp + 512);
}

// LDS-tiled transpose prep: coalesced reads AND writes.
__global__ __launch_bounds__(256)
void prep_kernel(const float* __restrict__ W1a, const float* __restrict__ W2a,
                 const float* __restrict__ W3a, const float* __restrict__ W4a,
                 const float* __restrict__ W1b, const float* __restrict__ W2b,
                 const float* __restrict__ W3b, const float* __restrict__ W4b,
                 const float* __restrict__ Wf,  u16* __restrict__ ws) {
    __shared__ __align__(16) u16 T[64 * 80];

    const int y = blockIdx.y;
    const int t = threadIdx.x;
    const float* in;
    int K, N;
    if (y < 4)      { in = (y == 0) ? W1a : (y == 1) ? W2a : (y == 2) ? W3a : W4a; K = 256; N = 256; }
    else if (y < 8) { in = (y == 4) ? W1b : (y == 5) ? W2b : (y == 6) ? W3b : W4b; K = 256; N = 128; }
    else            { in = Wf; K = 545; N = 128; }

    const int ntilesN = N / 64;
    const int ktiles = (K + 63) / 64;
    const int kt = blockIdx.x / ntilesN;
    const int nt = blockIdx.x - kt * ntilesN;
    if (kt >= ktiles) return;
    const int kbase = kt * 64, nbase = nt * 64;

    {
        int tn = (t & 15) * 4;
        int tk = t >> 4;
        #pragma unroll
        for (int r = 0; r < 4; r++) {
            int k = kbase + tk + 16 * r;
            if (k < K) {
                float4 v = *(const float4*)(in + (size_t)k * N + nbase + tn);
                T[(tn + 0) * 80 + tk + 16 * r] = f2b(v.x);
                T[(tn + 1) * 80 + tk + 16 * r] = f2b(v.y);
                T[(tn + 2) * 80 + tk + 16 * r] = f2b(v.z);
                T[(tn + 3) * 80 + tk + 16 * r] = f2b(v.w);
            }
        }
    }
    __syncthreads();
    {
        int n = t >> 2;
        int kc = (t & 3) * 16;
        int n_out = nbase + n;
        const u16* src = &T[n * 80 + kc];
        if (y < 4) {
            u16* dst = ws + OFF_WA + y * 65536 + (size_t)n_out * 256 + kbase + kc;
            *(short8*)dst = *(const short8*)src;
            *(short8*)(dst + 8) = *(const short8*)(src + 8);
        } else if (y < 8) {
            u16* dst = ws + OFF_WB + (y - 4) * 32768 + (size_t)n_out * 256 + kbase + kc;
            *(short8*)dst = *(const short8*)src;
            *(short8*)(dst + 8) = *(const short8*)(src + 8);
        } else if (kbase < 512) {
            u16* dst = ws + OFF_WF + (kbase >> 7) * 16384 + (size_t)n_out * 128 + (kbase & 127) + kc;
            *(short8*)dst = *(const short8*)src;
            *(short8*)(dst + 8) = *(const short8*)(src + 8);
        } else {
            #pragma unroll
            for (int j = 0; j < 16; j++) {
                int k = kbase + kc + j;
                if (k < 545) {
                    u16 v = src[j];
                    if (k == 512)      ws[OFF_WS + n_out] = v;
                    else               ws[OFF_WE + n_out * 32 + (k - 513)] = v;
                }
            }
        }
    }
}

// 32 edges/block, 4 waves, ~74 KB LDS -> 2 blocks/CU.
// Depth-2 counted-vmcnt weight pipeline (see issue_chunk). Stage barriers are
// plain __syncthreads() (their implicit vmcnt drain keeps the manual counts
// trivially conservative). 10 barriers/block total vs 56 in the round-0 code.
__global__ __launch_bounds__(256, 2)
void fused_kernel(const float* __restrict__ x, const int* __restrict__ ei,
                  const float* __restrict__ ea, const u16* __restrict__ ws,
                  BiasP bp, const float* __restrict__ bfp, float* __restrict__ out) {
    __shared__ __align__(16) u16 Xs[32][264];
    __shared__ __align__(16) u16 Xd[32][264];
    __shared__ __align__(16) u16 Hs[32][264];
    __shared__ __align__(16) u16 Gs[32][136];
    __shared__ __align__(16) u16 Wb[8192];   // 16 KB, 4-KB quarter per wave
    __shared__ float scos[32];

    const int t = threadIdx.x;
    const int wave = t >> 6;
    const int lane = t & 63;
    const int l15 = lane & 15;
    const int g = lane >> 4;
    const int e0 = blockIdx.x * 32;
    const f32x4 zero4 = {0.f, 0.f, 0.f, 0.f};

    // Hedge: detect int64 edge_index (sampled high words all zero) vs int32.
    bool idx64 = true;
    #pragma unroll
    for (int i = 1; i < 16; i += 2) { idx64 = idx64 && (ei[i] == 0); }

    const int colA = wave * 64;
    const int colC = wave * 32;

    // ---- hoisted constants FIRST (so their vmcnt retires before chunk 0's wait) ----
    short8 eaA[2];
    #pragma unroll
    for (int mt = 0; mt < 2; mt++) {
        const float* er = ea + (size_t)(e0 + mt * 16 + l15) * 32 + g * 8;
        f32x4 a = *(const f32x4*)(er);
        f32x4 b = *(const f32x4*)(er + 4);
        eaA[mt] = pack8(a, b);
    }
    short8 eaB[2];
    float epi_b[2], epi_w[2];
    #pragma unroll
    for (int nt = 0; nt < 2; nt++) {
        int col = colC + nt * 16 + l15;
        eaB[nt] = *(const short8*)(ws + OFF_WE + col * 32 + g * 8);
        epi_b[nt] = bfp[col];
        epi_w[nt] = b2f(ws[OFF_WS + col]);
    }
    float biasA[4][4], biasB[4][2];
    #pragma unroll
    for (int m = 0; m < 4; m++) {
        #pragma unroll
        for (int nt = 0; nt < 4; nt++) biasA[m][nt] = bp.ba[m][colA + nt * 16 + l15];
        #pragma unroll
        for (int nt = 0; nt < 2; nt++) biasB[m][nt] = bp.bb[m][colC + nt * 16 + l15];
    }

    // fire the first two chunks; they land during the gather
    issue_chunk(ws, Wb, wave, lane, 0);
    issue_chunk(ws, Wb, wave, lane, 1);

    // ---- gather (f32 -> bf16 tiles) + cosine similarity in one pass ----
    {
        int edge = t >> 3;
        int c = t & 7;
        int pos = e0 + edge;
        int is = idx64 ? ei[2 * pos] : ei[pos];
        int id = idx64 ? ei[2 * (NE + pos)] : ei[NE + pos];
        const float* rs = x + (size_t)is * 256 + c * 32;
        const float* rd = x + (size_t)id * 256 + c * 32;
        float dot = 0.f, ss = 0.f, dd = 0.f;
        #pragma unroll
        for (int i = 0; i < 4; i++) {
            f32x4 s0 = *(const f32x4*)(rs + i * 8);
            f32x4 s1 = *(const f32x4*)(rs + i * 8 + 4);
            f32x4 d0 = *(const f32x4*)(rd + i * 8);
            f32x4 d1 = *(const f32x4*)(rd + i * 8 + 4);
            dot += s0.x * d0.x + s0.y * d0.y + s0.z * d0.z + s0.w * d0.w
                 + s1.x * d1.x + s1.y * d1.y + s1.z * d1.z + s1.w * d1.w;
            ss  += s0.x * s0.x + s0.y * s0.y + s0.z * s0.z + s0.w * s0.w
                 + s1.x * s1.x + s1.y * s1.y + s1.z * s1.z + s1.w * s1.w;
            dd  += d0.x * d0.x + d0.y * d0.y + d0.z * d0.z + d0.w * d0.w
                 + d1.x * d1.x + d1.y * d1.y + d1.z * d1.z + d1.w * d1.w;
            *(short8*)(&Xs[edge][c * 32 + i * 8]) = pack8(s0, s1);
            *(short8*)(&Xd[edge][c * 32 + i * 8]) = pack8(d0, d1);
        }
        dot += __shfl_xor(dot, 1); ss += __shfl_xor(ss, 1); dd += __shfl_xor(dd, 1);
        dot += __shfl_xor(dot, 2); ss += __shfl_xor(ss, 2); dd += __shfl_xor(dd, 2);
        dot += __shfl_xor(dot, 4); ss += __shfl_xor(ss, 4); dd += __shfl_xor(dd, 4);
        if (c == 0) {
            float ns = fmaxf(sqrtf(ss), 1e-8f);
            float nd = fmaxf(sqrtf(dd), 1e-8f);
            scos[edge] = dot / (ns * nd);
        }
    }
    __syncthreads();   // gather barrier: Xs/Xd/scos visible (also drains c0,c1 - fine)

    // ---- LDS read base pointers ----
    const u16* xsb0 = &Xs[l15][g * 8];      const u16* xsb1 = &Xs[16 + l15][g * 8];
    const u16* xdb0 = &Xd[l15][g * 8];      const u16* xdb1 = &Xd[16 + l15][g * 8];
    const u16* hrb0 = &Hs[l15][g * 8];      const u16* hrb1 = &Hs[16 + l15][g * 8];
    const u16* grb0 = &Gs[l15][g * 8];      const u16* grb1 = &Gs[16 + l15][g * 8];
    // weight frag base: row = nt*16 + l15, k-slot g XOR-swizzled by (l15>>1)&3
    const u16* wbase = Wb + wave * 2048 + l15 * 32 + ((g ^ ((l15 >> 1) & 3)) * 8);

    f32x4 Facc[2][2];
    #pragma unroll
    for (int a = 0; a < 2; a++) {
        #pragma unroll
        for (int b = 0; b < 2; b++) Facc[a][b] = zero4;
    }

    #pragma unroll
    for (int m = 0; m < 4; m++) {
        // ===== stage A: H = relu(A @ Wa + ba) ===== (16 chunks: 8 kk x 2 col-halves)
        f32x4 accA[2][4];
        #pragma unroll
        for (int a = 0; a < 2; a++) {
            #pragma unroll
            for (int b = 0; b < 4; b++) accA[a][b] = zero4;
        }
        #pragma unroll
        for (int kk = 0; kk < 8; kk++) {
            const int gc = m * 28 + kk * 2;
            // X frags first (stable LDS, independent of DMA wait)
            short8 s0, s1, d0, d1;
            if (m != 1) { s0 = *(const short8*)(xsb0 + kk * 32); s1 = *(const short8*)(xsb1 + kk * 32); }
            if (m != 0) { d0 = *(const short8*)(xdb0 + kk * 32); d1 = *(const short8*)(xdb1 + kk * 32); }
            // ---- chunk gc (col-half 0) ----
            WAIT2();
            const u16* wq0 = wbase + (gc & 1) * 1024;
            short8 wf0 = *(const short8*)(wq0);
            short8 wf1 = *(const short8*)(wq0 + 512);
            LGKM0();
            issue_chunk(ws, Wb, wave, lane, gc + 2);
            short8 af0, af1;
            if (m == 0)      { af0 = s0; af1 = s1; }
            else if (m == 1) { af0 = d0; af1 = d1; }
            else {
                #pragma unroll
                for (int mt = 0; mt < 2; mt++) {
                    short8 s = mt ? s1 : s0, d = mt ? d1 : d0, rr;
                    #pragma unroll
                    for (int j = 0; j < 8; j++) {
                        float fs = b2f((u16)s[j]);
                        float fd = b2f((u16)d[j]);
                        rr[j] = (short)f2b((m == 2) ? (fs - fd) : (fs * fd));
                    }
                    if (mt) af1 = rr; else af0 = rr;
                }
            }
            accA[0][0] = MFMA16(af0, wf0, accA[0][0]);
            accA[1][0] = MFMA16(af1, wf0, accA[1][0]);
            accA[0][1] = MFMA16(af0, wf1, accA[0][1]);
            accA[1][1] = MFMA16(af1, wf1, accA[1][1]);
            // ---- chunk gc+1 (col-half 1) ----
            WAIT2();
            const u16* wq1 = wbase + ((gc + 1) & 1) * 1024;
            short8 wf2 = *(const short8*)(wq1);
            short8 wf3 = *(const short8*)(wq1 + 512);
            LGKM0();
            issue_chunk(ws, Wb, wave, lane, gc + 3);
            accA[0][2] = MFMA16(af0, wf2, accA[0][2]);
            accA[1][2] = MFMA16(af1, wf2, accA[1][2]);
            accA[0][3] = MFMA16(af0, wf3, accA[0][3]);
            accA[1][3] = MFMA16(af1, wf3, accA[1][3]);
        }
        #pragma unroll
        for (int nt = 0; nt < 4; nt++) {
            int col = colA + nt * 16 + l15;
            #pragma unroll
            for (int mt = 0; mt < 2; mt++) {
                #pragma unroll
                for (int rg = 0; rg < 4; rg++) {
                    int row = mt * 16 + g * 4 + rg;
                    Hs[row][col] = f2b(fmaxf(accA[mt][nt][rg] + biasA[m][nt], 0.f));
                }
            }
        }
        __syncthreads();                         // BARRIER_A: Hs ready

        // ===== stage B: G = relu(H @ Wb + bb) ===== (8 chunks of 32-k)
        f32x4 accB[2][2];
        #pragma unroll
        for (int a = 0; a < 2; a++) {
            #pragma unroll
            for (int b = 0; b < 2; b++) accB[a][b] = zero4;
        }
        #pragma unroll
        for (int kc = 0; kc < 8; kc++) {
            const int gc = m * 28 + 16 + kc;
            short8 hf0 = *(const short8*)(hrb0 + kc * 32);
            short8 hf1 = *(const short8*)(hrb1 + kc * 32);
            WAIT2();
            const u16* wq = wbase + (gc & 1) * 1024;
            short8 wf0 = *(const short8*)(wq);
            short8 wf1 = *(const short8*)(wq + 512);
            LGKM0();
            issue_chunk(ws, Wb, wave, lane, gc + 2);
            accB[0][0] = MFMA16(hf0, wf0, accB[0][0]);
            accB[1][0] = MFMA16(hf1, wf0, accB[1][0]);
            accB[0][1] = MFMA16(hf0, wf1, accB[0][1]);
            accB[1][1] = MFMA16(hf1, wf1, accB[1][1]);
        }
        #pragma unroll
        for (int nt = 0; nt < 2; nt++) {
            int col = colC + nt * 16 + l15;
            #pragma unroll
            for (int mt = 0; mt < 2; mt++) {
                #pragma unroll
                for (int rg = 0; rg < 4; rg++) {
                    int row = mt * 16 + g * 4 + rg;
                    Gs[row][col] = f2b(fmaxf(accB[mt][nt][rg] + biasB[m][nt], 0.f));
                }
            }
        }
        __syncthreads();                         // BARRIER_B: Gs ready

        // ===== stage C: Facc += G @ WfT_m ===== (4 chunks of 32-k)
        #pragma unroll
        for (int cc = 0; cc < 4; cc++) {
            const int gc = m * 28 + 24 + cc;
            short8 gf0 = *(const short8*)(grb0 + cc * 32);
            short8 gf1 = *(const short8*)(grb1 + cc * 32);
            if (m == 3 && cc == 3) { VM0(); } else { WAIT2(); }
            const u16* wq = wbase + (gc & 1) * 1024;
            short8 wf0 = *(const short8*)(wq);
            short8 wf1 = *(const short8*)(wq + 512);
            LGKM0();
            issue_chunk(ws, Wb, wave, lane, gc + 2);
            Facc[0][0] = MFMA16(gf0, wf0, Facc[0][0]);
            Facc[1][0] = MFMA16(gf1, wf0, Facc[1][0]);
            Facc[0][1] = MFMA16(gf0, wf1, Facc[0][1]);
            Facc[1][1] = MFMA16(gf1, wf1, Facc[1][1]);
        }
        // no barrier here: next A reads only Xs/Xd (stable) + private Wb;
        // Gs overwrite in B(m+1) is fenced by BARRIER_A(m+1).
    }

    // ===== edge_attr contribution (fragments pre-loaded) =====
    #pragma unroll
    for (int mt = 0; mt < 2; mt++) {
        #pragma unroll
        for (int nt = 0; nt < 2; nt++) {
            Facc[mt][nt] = MFMA16(eaA[mt], eaB[nt], Facc[mt][nt]);
        }
    }

    // ===== epilogue: + s*Wf[512] + bf, tanh, stage f32 in LDS, coalesced store =====
    float* os = (float*)&Xs[0][0];   // reuse Xs: 32 x 132 f32 = 16896 B (exact fit)
    #pragma unroll
    for (int nt = 0; nt < 2; nt++) {
        int col = colC + nt * 16 + l15;
        #pragma unroll
        for (int mt = 0; mt < 2; mt++) {
            #pragma unroll
            for (int rg = 0; rg < 4; rg++) {
                int row = mt * 16 + g * 4 + rg;
                float v = Facc[mt][nt][rg] + scos[row] * epi_w[nt] + epi_b[nt];
                v = fminf(fmaxf(v, -15.f), 15.f);
                float e2 = __expf(2.f * v);
                os[row * 132 + col] = (e2 - 1.f) / (e2 + 1.f);
            }
        }
    }
    __syncthreads();
    {
        int row = t >> 3, c = t & 7;
        float* op = out + (size_t)(e0 + row) * 128 + c * 16;
        const float* sp = os + row * 132 + c * 16;
        #pragma unroll
        for (int i = 0; i < 4; i++) {
            f32x4 v = *(const f32x4*)(sp + i * 4);
            *(f32x4*)(op + i * 4) = v;
        }
    }
}

extern "C" void kernel_launch(void* const* d_in, const int* in_sizes, int n_in,
                              void* d_out, int out_size, void* d_ws, size_t ws_size,
                              hipStream_t stream) {
    u16* ws = (u16*)d_ws;
    prep_kernel<<<dim3(18, 9), 256, 0, stream>>>(
        (const float*)d_in[3],  (const float*)d_in[7],  (const float*)d_in[11], (const float*)d_in[15],
        (const float*)d_in[5],  (const float*)d_in[9],  (const float*)d_in[13], (const float*)d_in[17],
        (const float*)d_in[19], ws);

    BiasP bp;
    bp.ba[0] = (const float*)d_in[4];  bp.ba[1] = (const float*)d_in[8];
    bp.ba[2] = (const float*)d_in[12]; bp.ba[3] = (const float*)d_in[16];
    bp.bb[0] = (const float*)d_in[6];  bp.bb[1] = (const float*)d_in[10];
    bp.bb[2] = (const float*)d_in[14]; bp.bb[3] = (const float*)d_in[18];

    fused_kernel<<<NE / 32, 256, 0, stream>>>(
        (const float*)d_in[0], (const int*)d_in[1], (const float*)d_in[2], ws,
        bp, (const float*)d_in[20], (float*)d_out);
}